// Round 1
// baseline (2896.332 us; speedup 1.0000x reference)
//
#include <hip/hip_runtime.h>
#include <hip/hip_bf16.h>

#define LOG2E 1.4426950408889634f

__device__ __forceinline__ float fexp(float x){ return __builtin_amdgcn_exp2f(x * LOG2E); }
__device__ __forceinline__ float frcp(float x){ return __builtin_amdgcn_rcpf(x); }
__device__ __forceinline__ float tanh_fast(float x){ float e = fexp(2.f*x); return 1.f - 2.f*frcp(e + 1.f); }
__device__ __forceinline__ float sigm_fast(float x){ return frcp(1.f + fexp(-x)); }
__device__ __forceinline__ float elu_fast(float x){ return x > 0.f ? x : fexp(x) - 1.f; }
__device__ __forceinline__ float dot4(float4 a, float4 b){
  return (a.x*b.x + a.y*b.y) + (a.z*b.z + a.w*b.w);
}
__device__ __forceinline__ float wsum(float v){
  #pragma unroll
  for (int o = 32; o > 0; o >>= 1) v += __shfl_xor(v, o, 64);
  return v;
}
__device__ __forceinline__ float wmax(float v){
  #pragma unroll
  for (int o = 32; o > 0; o >>= 1) v = fmaxf(v, __shfl_xor(v, o, 64));
  return v;
}

// ---------------------------------------------------------------------------
// K0: pack/transpose weights into workspace (output index contiguous, float4 k-chunks)
//  Wd4 [k4=0..31][j=0..127]  = FC1_w[j][4k4..]      (d part, cols 0..127)
//  Ws4 [k4=0..31][j=0..127]  = FC1_w[j][128+4k4..]  (s part)
//  Whh4[k4=0..31][j=0..511]  = W_hh[j][4k4..]
//  Fo14[k4=0..63][j=0..127]  = FCout1_w[j][4k4..]
//  bio [j=0..511]            = b_ih[j] + b_hh[j]
// ---------------------------------------------------------------------------
__global__ void k_prep(const float* __restrict__ FC1_w, const float* __restrict__ W_hh,
                       const float* __restrict__ FCout1_w,
                       const float* __restrict__ b_ih, const float* __restrict__ b_hh,
                       float4* __restrict__ Wd4, float4* __restrict__ Ws4,
                       float4* __restrict__ Whh4, float4* __restrict__ Fo14,
                       float* __restrict__ bio)
{
  int n = blockIdx.x * 256 + threadIdx.x;
  if (n < 4096) {
    int k4 = n >> 7, j = n & 127;
    const float* p = FC1_w + j*384 + 4*k4;
    Wd4[n] = make_float4(p[0], p[1], p[2], p[3]);
    Ws4[n] = make_float4(p[128], p[129], p[130], p[131]);
  }
  int n2 = n - 4096;
  if (n2 >= 0 && n2 < 16384) {
    int k4 = n2 >> 9, j = n2 & 511;
    const float* p = W_hh + j*128 + 4*k4;
    Whh4[n2] = make_float4(p[0], p[1], p[2], p[3]);
  }
  int n3 = n - 20480;
  if (n3 >= 0 && n3 < 8192) {
    int k4 = n3 >> 7, j = n3 & 127;
    const float* p = FCout1_w + j*256 + 4*k4;
    Fo14[n3] = make_float4(p[0], p[1], p[2], p[3]);
  }
  int n4 = n - 28672;
  if (n4 >= 0 && n4 < 512) bio[n4] = b_ih[n4] + b_hh[n4];
}

// ---------------------------------------------------------------------------
// K1: HWt[b][m][t] = sum_k FC1_w[m][256+k] * H[b][t][k] + FC1_b[m]   (bf16)
// one block per batch row; H row staged in LDS
// ---------------------------------------------------------------------------
__global__ __launch_bounds__(256) void k_hw(
    const float* __restrict__ H, const float* __restrict__ FC1_w,
    const float* __restrict__ FC1_b, __hip_bfloat16* __restrict__ HWt)
{
  __shared__ float Hl[64][128];
  const int b = blockIdx.x, tid = threadIdx.x;
  const float* Hb = H + (size_t)b * 8192;
  for (int i = tid; i < 8192; i += 256) ((float*)Hl)[i] = Hb[i];
  __syncthreads();

  const int m = tid >> 1, t0 = (tid & 1) * 32;
  float acc[32];
  const float bias = FC1_b[m];
  #pragma unroll
  for (int j = 0; j < 32; ++j) acc[j] = bias;

  const float* wrow = FC1_w + m*384 + 256;
  for (int k4 = 0; k4 < 32; ++k4) {
    float4 w = *(const float4*)(wrow + 4*k4);
    #pragma unroll
    for (int j = 0; j < 32; ++j) {
      float4 h = *(const float4*)&Hl[t0 + j][4*k4];
      acc[j] += dot4(w, h);
    }
  }
  __hip_bfloat16* o = HWt + (size_t)b*8192 + m*64 + t0;
  #pragma unroll
  for (int j = 0; j < 32; ++j) o[j] = __float2bfloat16(acc[j]);
}

// ---------------------------------------------------------------------------
// K2: main recurrence. 8 waves/block, one wave per batch row, 64 steps.
// ---------------------------------------------------------------------------
__global__ __launch_bounds__(512) void k_main(
    const float* __restrict__ H, const float* __restrict__ Y,
    const __hip_bfloat16* __restrict__ HWt,
    const float4* __restrict__ Wd4, const float4* __restrict__ Ws4,
    const float4* __restrict__ Whh4, const float4* __restrict__ Fo14,
    const float* __restrict__ bio,
    const float* __restrict__ FC2_w,
    const float* __restrict__ FCin_w, const float* __restrict__ FCin_b,
    const float* __restrict__ W_ih,
    const float* __restrict__ FCout1_b,
    const float* __restrict__ FCout2_w, const float* __restrict__ FCout2_b,
    float* __restrict__ out, int L)
{
  __shared__ float a_l[8][128], d_l[8][128], s_l[8][128], c_l[8][128];
  __shared__ float alpha_l[8][64];
  __shared__ float fc2s[128], fo2s[128], fo1bs[128], fcins[132], bios[512], wihs[512], scal[4];

  const int tid = threadIdx.x, w = tid >> 6, lane = tid & 63;
  if (tid < 128) { fc2s[tid] = FC2_w[tid]; fo2s[tid] = FCout2_w[tid]; fo1bs[tid] = FCout1_b[tid]; }
  if (tid < 129) fcins[tid] = FCin_w[tid];
  bios[tid & 511] = bio[tid & 511];
  wihs[tid & 511] = W_ih[tid & 511];
  if (tid == 0) { scal[1] = FCin_b[0]; scal[2] = FCout2_b[0]; }

  d_l[w][lane] = 0.f; d_l[w][lane + 64] = 0.f;
  s_l[w][lane] = 0.f; s_l[w][lane + 64] = 0.f;
  __syncthreads();

  const int b = blockIdx.x * 8 + w;
  const float* Hb = H + (size_t)b * 8192;
  const __hip_bfloat16* HWb = HWt + (size_t)b * 8192;
  float dA = 0.f, dB = 0.f, sA = 0.f, sB = 0.f;

  for (int step = 0; step < L; ++step) {
    // ---- 1. a = Wd*d + Ws*s  (this wave's row; outputs a[lane], a[lane+64])
    float a0d = 0.f, a0s = 0.f, a1d = 0.f, a1s = 0.f;
    #pragma unroll 4
    for (int k4 = 0; k4 < 32; ++k4) {
      float4 dv = *(const float4*)&d_l[w][4*k4];
      float4 sv = *(const float4*)&s_l[w][4*k4];
      a0d += dot4(Wd4[k4*128 + lane],      dv);
      a1d += dot4(Wd4[k4*128 + 64 + lane], dv);
      a0s += dot4(Ws4[k4*128 + lane],      sv);
      a1s += dot4(Ws4[k4*128 + 64 + lane], sv);
    }
    a_l[w][lane] = a0d + a0s;
    a_l[w][lane + 64] = a1d + a1s;

    // ---- 2. logits over m (lane = t)
    float lg0 = 0.f, lg1 = 0.f;
    #pragma unroll 4
    for (int m = 0; m < 128; m += 2) {
      float hw0 = __bfloat162float(HWb[m*64 + lane]);
      float hw1 = __bfloat162float(HWb[(m+1)*64 + lane]);
      lg0 += fc2s[m]   * tanh_fast(a_l[w][m]   + hw0);
      lg1 += fc2s[m+1] * tanh_fast(a_l[w][m+1] + hw1);
    }
    float lg = lg0 + lg1;

    // ---- 3. softmax over T (64 lanes)
    float mx = wmax(lg);
    float ex = fexp(lg - mx);
    float sm = wsum(ex);
    alpha_l[w][lane] = ex / sm;

    // ---- 4. C = sum_t alpha_t * H[t]   (lane = m, two halves)
    float c0 = 0.f, c1 = 0.f;
    #pragma unroll 4
    for (int t = 0; t < 64; ++t) {
      float al = alpha_l[w][t];
      c0 += al * Hb[t*128 + lane];
      c1 += al * Hb[t*128 + 64 + lane];
    }
    c_l[w][lane] = c0; c_l[w][lane + 64] = c1;

    // ---- 5. lstm_in
    float part = fcins[1 + lane]*c0 + fcins[65 + lane]*c1;
    part = wsum(part);
    float yt = Y[(size_t)b*64 + step];
    float li = part + fcins[0]*yt + scal[1];

    // ---- 6. gates (i,f,g,o), j = c*64+lane for chunk c
    float g0=0.f,g1=0.f,g2=0.f,g3=0.f,g4=0.f,g5=0.f,g6=0.f,g7=0.f;
    #pragma unroll 2
    for (int k4 = 0; k4 < 32; ++k4) {
      float4 dv = *(const float4*)&d_l[w][4*k4];
      g0 += dot4(Whh4[k4*512 +   0 + lane], dv);
      g1 += dot4(Whh4[k4*512 +  64 + lane], dv);
      g2 += dot4(Whh4[k4*512 + 128 + lane], dv);
      g3 += dot4(Whh4[k4*512 + 192 + lane], dv);
      g4 += dot4(Whh4[k4*512 + 256 + lane], dv);
      g5 += dot4(Whh4[k4*512 + 320 + lane], dv);
      g6 += dot4(Whh4[k4*512 + 384 + lane], dv);
      g7 += dot4(Whh4[k4*512 + 448 + lane], dv);
    }
    g0 += li*wihs[lane]       + bios[lane];
    g1 += li*wihs[64 + lane]  + bios[64 + lane];
    g2 += li*wihs[128 + lane] + bios[128 + lane];
    g3 += li*wihs[192 + lane] + bios[192 + lane];
    g4 += li*wihs[256 + lane] + bios[256 + lane];
    g5 += li*wihs[320 + lane] + bios[320 + lane];
    g6 += li*wihs[384 + lane] + bios[384 + lane];
    g7 += li*wihs[448 + lane] + bios[448 + lane];
    // i = g0,g1 ; f = g2,g3 ; g = g4,g5 ; o = g6,g7
    float iA = sigm_fast(g0), iB = sigm_fast(g1);
    float fA = sigm_fast(g2), fB = sigm_fast(g3);
    float gA = tanh_fast(g4), gB = tanh_fast(g5);
    float oA = sigm_fast(g6), oB = sigm_fast(g7);
    sA = fA*sA + iA*gA;  sB = fB*sB + iB*gB;
    dA = oA*tanh_fast(sA);  dB = oB*tanh_fast(sB);
    d_l[w][lane] = dA; d_l[w][lane + 64] = dB;
    s_l[w][lane] = sA; s_l[w][lane + 64] = sB;

    // ---- 7. output MLP: h = elu(FCout1 * [d_new, C] + b); out = FCout2 * h + b
    float h0 = fo1bs[lane], h1 = fo1bs[64 + lane];
    #pragma unroll 4
    for (int k4 = 0; k4 < 32; ++k4) {
      float4 v = *(const float4*)&d_l[w][4*k4];
      h0 += dot4(Fo14[k4*128 + lane],      v);
      h1 += dot4(Fo14[k4*128 + 64 + lane], v);
    }
    #pragma unroll 4
    for (int k4 = 0; k4 < 32; ++k4) {
      float4 v = *(const float4*)&c_l[w][4*k4];
      h0 += dot4(Fo14[(32 + k4)*128 + lane],      v);
      h1 += dot4(Fo14[(32 + k4)*128 + 64 + lane], v);
    }
    h0 = elu_fast(h0); h1 = elu_fast(h1);
    float op = fo2s[lane]*h0 + fo2s[64 + lane]*h1;
    op = wsum(op);
    if (lane == 0) out[(size_t)b*64 + step] = op + scal[2];

    __syncthreads();  // keep waves in lockstep for weight L1 reuse
  }
}

extern "C" void kernel_launch(void* const* d_in, const int* in_sizes, int n_in,
                              void* d_out, int out_size, void* d_ws, size_t ws_size,
                              hipStream_t stream) {
  const float* H        = (const float*)d_in[0];
  const float* y        = (const float*)d_in[1];
  const float* FC1_w    = (const float*)d_in[2];
  const float* FC1_b    = (const float*)d_in[3];
  const float* FC2_w    = (const float*)d_in[4];
  // d_in[5] = FC2_b (softmax-invariant, unused)
  const float* FCin_w   = (const float*)d_in[6];
  const float* FCin_b   = (const float*)d_in[7];
  const float* W_ih     = (const float*)d_in[8];
  const float* W_hh     = (const float*)d_in[9];
  const float* b_ih     = (const float*)d_in[10];
  const float* b_hh     = (const float*)d_in[11];
  const float* FCout1_w = (const float*)d_in[12];
  const float* FCout1_b = (const float*)d_in[13];
  const float* FCout2_w = (const float*)d_in[14];
  const float* FCout2_b = (const float*)d_in[15];
  float* out = (float*)d_out;
  const int L = out_size / 2048;   // target_length (= 64)

  char* ws = (char*)d_ws;
  __hip_bfloat16* HWt = (__hip_bfloat16*)ws;               // 2048*128*64*2 = 33554432 B
  float4* Wd4  = (float4*)(ws + 33554432);                 // 65536 B
  float4* Ws4  = (float4*)(ws + 33554432 + 65536);         // 65536 B
  float4* Whh4 = (float4*)(ws + 33554432 + 131072);        // 262144 B
  float4* Fo14 = (float4*)(ws + 33554432 + 393216);        // 131072 B
  float*  bio  = (float*)(ws + 33554432 + 524288);         // 2048 B

  k_prep<<<114, 256, 0, stream>>>(FC1_w, W_hh, FCout1_w, b_ih, b_hh,
                                  Wd4, Ws4, Whh4, Fo14, bio);
  k_hw<<<2048, 256, 0, stream>>>(H, FC1_w, FC1_b, HWt);
  k_main<<<256, 512, 0, stream>>>(H, y, HWt, Wd4, Ws4, Whh4, Fo14, bio,
                                  FC2_w, FCin_w, FCin_b, W_ih,
                                  FCout1_b, FCout2_w, FCout2_b, out, L);
}

// Round 2
// 2630.879 us; speedup vs baseline: 1.1009x; 1.1009x over previous
//
#include <hip/hip_runtime.h>
#include <hip/hip_bf16.h>

#define LOG2E 1.4426950408889634f

__device__ __forceinline__ float fexp(float x){ return __builtin_amdgcn_exp2f(x * LOG2E); }
__device__ __forceinline__ float frcp(float x){ return __builtin_amdgcn_rcpf(x); }
__device__ __forceinline__ float tanh_fast(float x){ float e = fexp(2.f*x); return 1.f - 2.f*frcp(e + 1.f); }
__device__ __forceinline__ float sigm_fast(float x){ return frcp(1.f + fexp(-x)); }
__device__ __forceinline__ float elu_fast(float x){ return x > 0.f ? x : fexp(x) - 1.f; }
__device__ __forceinline__ float dot4(float4 a, float4 b){
  return (a.x*b.x + a.y*b.y) + (a.z*b.z + a.w*b.w);
}
__device__ __forceinline__ float wsum(float v){
  #pragma unroll
  for (int o = 32; o > 0; o >>= 1) v += __shfl_xor(v, o, 64);
  return v;
}
__device__ __forceinline__ float wmax(float v){
  #pragma unroll
  for (int o = 32; o > 0; o >>= 1) v = fmaxf(v, __shfl_xor(v, o, 64));
  return v;
}

// ---------------------------------------------------------------------------
// K0: pack/transpose weights (output index contiguous, float4 k-chunks)
// ---------------------------------------------------------------------------
__global__ void k_prep(const float* __restrict__ FC1_w, const float* __restrict__ W_hh,
                       const float* __restrict__ FCout1_w,
                       const float* __restrict__ b_ih, const float* __restrict__ b_hh,
                       float4* __restrict__ Wd4, float4* __restrict__ Ws4,
                       float4* __restrict__ Whh4, float4* __restrict__ Fo14,
                       float* __restrict__ bio)
{
  int n = blockIdx.x * 256 + threadIdx.x;
  if (n < 4096) {
    int k4 = n >> 7, j = n & 127;
    const float* p = FC1_w + j*384 + 4*k4;
    Wd4[n] = make_float4(p[0], p[1], p[2], p[3]);
    Ws4[n] = make_float4(p[128], p[129], p[130], p[131]);
  }
  int n2 = n - 4096;
  if (n2 >= 0 && n2 < 16384) {
    int k4 = n2 >> 9, j = n2 & 511;
    const float* p = W_hh + j*128 + 4*k4;
    Whh4[n2] = make_float4(p[0], p[1], p[2], p[3]);
  }
  int n3 = n - 20480;
  if (n3 >= 0 && n3 < 8192) {
    int k4 = n3 >> 7, j = n3 & 127;
    const float* p = FCout1_w + j*256 + 4*k4;
    Fo14[n3] = make_float4(p[0], p[1], p[2], p[3]);
  }
  int n4 = n - 28672;
  if (n4 >= 0 && n4 < 512) bio[n4] = b_ih[n4] + b_hh[n4];
}

// ---------------------------------------------------------------------------
// K1: HWp[b][m4][t] = ushort4 of bf16( sum_k FC1_w[m][256+k]*H[b][t][k] + b[m] )
//     for m = 4*m4 .. 4*m4+3
// ---------------------------------------------------------------------------
__global__ __launch_bounds__(256) void k_hw(
    const float* __restrict__ H, const float* __restrict__ FC1_w,
    const float* __restrict__ FC1_b, unsigned short* __restrict__ HWp)
{
  __shared__ float Hl[64][128];
  const int b = blockIdx.x, tid = threadIdx.x;
  const float* Hb = H + (size_t)b * 8192;
  for (int i = tid; i < 8192; i += 256) ((float*)Hl)[i] = Hb[i];
  __syncthreads();

  const int m = tid >> 1, t0 = (tid & 1) * 32;
  float acc[32];
  const float bias = FC1_b[m];
  #pragma unroll
  for (int j = 0; j < 32; ++j) acc[j] = bias;

  const float* wrow = FC1_w + m*384 + 256;
  for (int k4 = 0; k4 < 32; ++k4) {
    float4 w = *(const float4*)(wrow + 4*k4);
    #pragma unroll
    for (int j = 0; j < 32; ++j) {
      float4 h = *(const float4*)&Hl[t0 + j][4*k4];
      acc[j] += dot4(w, h);
    }
  }
  // pack: HWp index = (((b*32 + m/4)*64) + t)*4 + (m&3)
  unsigned short* o = HWp + (((size_t)b*32 + (m >> 2))*64 + t0)*4 + (m & 3);
  #pragma unroll
  for (int j = 0; j < 32; ++j) {
    o[j*4] = (unsigned short)(__bfloat16_as_ushort(__float2bfloat16(acc[j])));
  }
}

// ---------------------------------------------------------------------------
// K2: main recurrence. 4 rows/block, 2 waves/row, 512 threads, 512 blocks.
// wave h owns output indices h*64+lane of all 128-wide vectors.
// ---------------------------------------------------------------------------
__global__ __launch_bounds__(512, 4) void k_main(
    const float* __restrict__ H, const float* __restrict__ Y,
    const unsigned short* __restrict__ HWp,
    const float4* __restrict__ Wd4, const float4* __restrict__ Ws4,
    const float4* __restrict__ Whh4, const float4* __restrict__ Fo14,
    const float* __restrict__ bio,
    const float* __restrict__ FC2_w,
    const float* __restrict__ FCin_w, const float* __restrict__ FCin_b,
    const float* __restrict__ W_ih,
    const float* __restrict__ FCout1_b,
    const float* __restrict__ FCout2_w, const float* __restrict__ FCout2_b,
    float* __restrict__ out, int L)
{
  __shared__ float d_l[2][4][128], s_l[2][4][128];
  __shared__ float c_l[4][128];
  __shared__ float lgp[4][2][64];
  __shared__ float redp[4][2], outp[4][2];
  __shared__ float fc2s[128], fo2s[128], fo1bs[128], fcins[132], bios[512], wihs[512], scal[4];

  const int tid = threadIdx.x, w = tid >> 6, lane = tid & 63;
  const int r = w >> 1, h = w & 1;
  const int oi = h*64 + lane;           // this thread's output index in [0,128)

  if (tid < 128) { fc2s[tid] = FC2_w[tid]; fo2s[tid] = FCout2_w[tid]; fo1bs[tid] = FCout1_b[tid]; }
  if (tid < 129) fcins[tid] = FCin_w[tid];
  bios[tid] = bio[tid];
  wihs[tid] = W_ih[tid];
  if (tid == 0) { scal[1] = FCin_b[0]; scal[2] = FCout2_b[0]; }

  d_l[0][r][oi] = 0.f; s_l[0][r][oi] = 0.f;
  __syncthreads();

  const int b = blockIdx.x * 4 + r;
  const float* Hb = H + (size_t)b * 8192;
  const uint2* HWb = (const uint2*)(HWp + ((size_t)b*32 + h*16)*64*4);
  float sA = 0.f;     // cell state for index oi (owned by this wave)
  int cur = 0;

  for (int step = 0; step < L; ++step) {
    const int nxt = cur ^ 1;
    // ---- 1. a[oi] = Wd[oi,:]*d + Ws[oi,:]*s   (in-register result)
    float ad = 0.f, as = 0.f;
    #pragma unroll 4
    for (int k4 = 0; k4 < 32; ++k4) {
      float4 dv = *(const float4*)&d_l[cur][r][4*k4];
      float4 sv = *(const float4*)&s_l[cur][r][4*k4];
      ad += dot4(Wd4[k4*128 + oi], dv);
      as += dot4(Ws4[k4*128 + oi], sv);
    }
    const float a_own = ad + as;

    // ---- 2. partial logits over this wave's m-half (lane = t)
    float lg = 0.f;
    #pragma unroll 4
    for (int m4l = 0; m4l < 16; ++m4l) {
      uint2 u = HWb[m4l*64 + lane];
      float f0 = __uint_as_float(u.x << 16);
      float f1 = __uint_as_float(u.x & 0xffff0000u);
      float f2 = __uint_as_float(u.y << 16);
      float f3 = __uint_as_float(u.y & 0xffff0000u);
      int ml = m4l*4;
      lg += fc2s[h*64+ml]   * tanh_fast(__shfl(a_own, ml)   + f0);
      lg += fc2s[h*64+ml+1] * tanh_fast(__shfl(a_own, ml+1) + f1);
      lg += fc2s[h*64+ml+2] * tanh_fast(__shfl(a_own, ml+2) + f2);
      lg += fc2s[h*64+ml+3] * tanh_fast(__shfl(a_own, ml+3) + f3);
    }
    lgp[r][h][lane] = lg;
    __syncthreads();                       // S1: lgp ready

    // ---- 3. softmax over T=64 (both waves redundantly)
    float lgt = lgp[r][0][lane] + lgp[r][1][lane];
    float mx = wmax(lgt);
    float ex = fexp(lgt - mx);
    float alpha = ex * frcp(wsum(ex));     // alpha for t = lane (in-register)

    // ---- 4. C[oi] = sum_t alpha_t * H[t][oi]
    float c = 0.f;
    #pragma unroll 4
    for (int t = 0; t < 64; ++t) {
      c += __shfl(alpha, t) * Hb[t*128 + oi];
    }
    c_l[r][oi] = c;

    // ---- 5. lstm_in partial
    float part = fcins[1 + oi] * c;
    part = wsum(part);
    if (lane == 0) redp[r][h] = part;
    __syncthreads();                       // S2: c_l + redp ready

    const float yt = Y[(size_t)b*64 + step];
    const float li = redp[r][0] + redp[r][1] + fcins[0]*yt + scal[1];

    // ---- 6. gates for state index oi: i,f,g,o rows = oi, 128+oi, 256+oi, 384+oi
    float gi = 0.f, gf = 0.f, gg = 0.f, go = 0.f;
    #pragma unroll 2
    for (int k4 = 0; k4 < 32; ++k4) {
      float4 dv = *(const float4*)&d_l[cur][r][4*k4];
      gi += dot4(Whh4[k4*512 +       oi], dv);
      gf += dot4(Whh4[k4*512 + 128 + oi], dv);
      gg += dot4(Whh4[k4*512 + 256 + oi], dv);
      go += dot4(Whh4[k4*512 + 384 + oi], dv);
    }
    gi += li*wihs[      oi] + bios[      oi];
    gf += li*wihs[128 + oi] + bios[128 + oi];
    gg += li*wihs[256 + oi] + bios[256 + oi];
    go += li*wihs[384 + oi] + bios[384 + oi];
    sA = sigm_fast(gf)*sA + sigm_fast(gi)*tanh_fast(gg);
    const float dA = sigm_fast(go)*tanh_fast(sA);
    d_l[nxt][r][oi] = dA;
    s_l[nxt][r][oi] = sA;
    __syncthreads();                       // S3: new d/s published

    // ---- 7. out MLP: h[oi] = elu(FCout1[oi,:]*[d_new, C] + b)
    float hacc = fo1bs[oi];
    #pragma unroll 4
    for (int k4 = 0; k4 < 32; ++k4) {
      float4 dv = *(const float4*)&d_l[nxt][r][4*k4];
      hacc += dot4(Fo14[k4*128 + oi], dv);
    }
    #pragma unroll 4
    for (int k4 = 0; k4 < 32; ++k4) {
      float4 cv = *(const float4*)&c_l[r][4*k4];
      hacc += dot4(Fo14[(32 + k4)*128 + oi], cv);
    }
    hacc = elu_fast(hacc);
    float op = fo2s[oi] * hacc;
    op = wsum(op);
    if (lane == 0) outp[r][h] = op;
    __syncthreads();                       // S4: outp ready
    if (h == 0 && lane == 0)
      out[(size_t)b*L + step] = outp[r][0] + outp[r][1] + scal[2];

    cur = nxt;
  }
}

extern "C" void kernel_launch(void* const* d_in, const int* in_sizes, int n_in,
                              void* d_out, int out_size, void* d_ws, size_t ws_size,
                              hipStream_t stream) {
  const float* H        = (const float*)d_in[0];
  const float* y        = (const float*)d_in[1];
  const float* FC1_w    = (const float*)d_in[2];
  const float* FC1_b    = (const float*)d_in[3];
  const float* FC2_w    = (const float*)d_in[4];
  // d_in[5] = FC2_b (softmax-invariant, unused)
  const float* FCin_w   = (const float*)d_in[6];
  const float* FCin_b   = (const float*)d_in[7];
  const float* W_ih     = (const float*)d_in[8];
  const float* W_hh     = (const float*)d_in[9];
  const float* b_ih     = (const float*)d_in[10];
  const float* b_hh     = (const float*)d_in[11];
  const float* FCout1_w = (const float*)d_in[12];
  const float* FCout1_b = (const float*)d_in[13];
  const float* FCout2_w = (const float*)d_in[14];
  const float* FCout2_b = (const float*)d_in[15];
  float* out = (float*)d_out;
  const int L = out_size / 2048;   // target_length (= 64)

  char* ws = (char*)d_ws;
  unsigned short* HWp = (unsigned short*)ws;               // 33554432 B
  float4* Wd4  = (float4*)(ws + 33554432);                 // 65536 B
  float4* Ws4  = (float4*)(ws + 33554432 + 65536);         // 65536 B
  float4* Whh4 = (float4*)(ws + 33554432 + 131072);        // 262144 B
  float4* Fo14 = (float4*)(ws + 33554432 + 393216);        // 131072 B
  float*  bio  = (float*)(ws + 33554432 + 524288);         // 2048 B

  k_prep<<<114, 256, 0, stream>>>(FC1_w, W_hh, FCout1_w, b_ih, b_hh,
                                  Wd4, Ws4, Whh4, Fo14, bio);
  k_hw<<<2048, 256, 0, stream>>>(H, FC1_w, FC1_b, HWp);
  k_main<<<512, 512, 0, stream>>>(H, y, HWp, Wd4, Ws4, Whh4, Fo14, bio,
                                  FC2_w, FCin_w, FCin_b, W_ih,
                                  FCout1_b, FCout2_w, FCout2_b, out, L);
}

// Round 3
// 830.143 us; speedup vs baseline: 3.4890x; 3.1692x over previous
//
#include <hip/hip_runtime.h>
#include <hip/hip_bf16.h>

typedef short bf16x8 __attribute__((ext_vector_type(8)));
typedef float f32x4 __attribute__((ext_vector_type(4)));

#define LOG2E 1.4426950408889634f

__device__ __forceinline__ float fexp(float x){ return __builtin_amdgcn_exp2f(x * LOG2E); }
__device__ __forceinline__ float frcp(float x){ return __builtin_amdgcn_rcpf(x); }
__device__ __forceinline__ float tanh_fast(float x){ float e = fexp(2.f*x); return 1.f - 2.f*frcp(e + 1.f); }
__device__ __forceinline__ float sigm_fast(float x){ return frcp(1.f + fexp(-x)); }
__device__ __forceinline__ float elu_fast(float x){ return x > 0.f ? x : fexp(x) - 1.f; }
__device__ __forceinline__ float dot4(float4 a, float4 b){
  return (a.x*b.x + a.y*b.y) + (a.z*b.z + a.w*b.w);
}
__device__ __forceinline__ float wsum(float v){
  #pragma unroll
  for (int o = 32; o > 0; o >>= 1) v += __shfl_xor(v, o, 64);
  return v;
}
__device__ __forceinline__ unsigned pk2(float a, float b){
  unsigned lo = __bfloat16_as_ushort(__float2bfloat16(a));
  unsigned hi = __bfloat16_as_ushort(__float2bfloat16(b));
  return lo | (hi << 16);
}
__device__ __forceinline__ float bflo(unsigned u){ return __uint_as_float(u << 16); }
__device__ __forceinline__ float bfhi(unsigned u){ return __uint_as_float(u & 0xffff0000u); }

// A-fragment LDS tile: [kt][lane][8 bf16] with XOR swizzle (read: ds_read_b128
// conflict-free; scattered b32 state-update writes land 4-way max).
__device__ __forceinline__ int afrag_off(int kt, int lanep){
  int off = (kt << 10) + (lanep << 4);
  off ^= ((lanep >> 4) & 1) << 5;
  off ^= (kt & 1) << 6;
  return off;
}

// ---------------------------------------------------------------------------
// K0: pack B-operand MFMA fragments (bf16) for the 3 GEMMs + bio.
// Fragment element: B[k][n], n = nt*16 + (lane&15), k = kt*32 + (lane>>4)*8 + j
// stored at ((nt*KT + kt)*64 + lane)*8 + j.
// ---------------------------------------------------------------------------
__global__ void k_prep(const float* __restrict__ FC1_w, const float* __restrict__ W_hh,
                       const float* __restrict__ FCout1_w,
                       const float* __restrict__ b_ih, const float* __restrict__ b_hh,
                       unsigned short* __restrict__ B1f, unsigned short* __restrict__ B2f,
                       unsigned short* __restrict__ B3f, float* __restrict__ bio)
{
  int n = blockIdx.x * 256 + threadIdx.x;
  if (n < 32768) {              // B1: Wds (K=256, N=128), NT=8 KT=8; B1[k][n]=FC1_w[n][k]
    int jj = n & 7, lane = (n >> 3) & 63, ktn = n >> 9;
    int kt = ktn & 7, nt = ktn >> 3;
    int nn = nt*16 + (lane & 15), k = kt*32 + ((lane >> 4) << 3) + jj;
    B1f[n] = __bfloat16_as_ushort(__float2bfloat16(FC1_w[nn*384 + k]));
  } else if (n < 98304) {       // B2: Whh (K=128, N=512), NT=32 KT=4
    int n2 = n - 32768;
    int jj = n2 & 7, lane = (n2 >> 3) & 63, ktn = n2 >> 9;
    int kt = ktn & 3, nt = ktn >> 2;
    int nn = nt*16 + (lane & 15), k = kt*32 + ((lane >> 4) << 3) + jj;
    B2f[n2] = __bfloat16_as_ushort(__float2bfloat16(W_hh[nn*128 + k]));
  } else if (n < 131072) {      // B3: Fo1 (K=256, N=128), NT=8 KT=8
    int n3 = n - 98304;
    int jj = n3 & 7, lane = (n3 >> 3) & 63, ktn = n3 >> 9;
    int kt = ktn & 7, nt = ktn >> 3;
    int nn = nt*16 + (lane & 15), k = kt*32 + ((lane >> 4) << 3) + jj;
    B3f[n3] = __bfloat16_as_ushort(__float2bfloat16(FCout1_w[nn*256 + k]));
  } else if (n < 131584) {
    int n4 = n - 131072;
    bio[n4] = b_ih[n4] + b_hh[n4];
  }
}

// ---------------------------------------------------------------------------
// K1: HWp[b][m4][t]{4 bf16} = FC1_w[m][256+k].H[b][t][k] + FC1_b[m];
//     optionally also H -> bf16 (Hbf) for the C-reduction.
// ---------------------------------------------------------------------------
__global__ __launch_bounds__(256) void k_hw(
    const float* __restrict__ H, const float* __restrict__ FC1_w,
    const float* __restrict__ FC1_b, unsigned short* __restrict__ HWp,
    unsigned short* __restrict__ Hbf)
{
  __shared__ __align__(16) float Hl[64][128];
  const int b = blockIdx.x, tid = threadIdx.x;
  const float* Hb = H + (size_t)b * 8192;
  for (int i = tid; i < 8192; i += 256) ((float*)Hl)[i] = Hb[i];
  __syncthreads();

  if (Hbf) {
    unsigned* Ho = (unsigned*)Hbf + (size_t)b * 4096;
    for (int i = tid; i < 4096; i += 256) {
      float2 v = ((const float2*)Hl)[i];
      Ho[i] = pk2(v.x, v.y);
    }
  }

  const int m = tid >> 1, t0 = (tid & 1) * 32;
  float acc[32];
  const float bias = FC1_b[m];
  #pragma unroll
  for (int j = 0; j < 32; ++j) acc[j] = bias;

  const float* wrow = FC1_w + m*384 + 256;
  for (int k4 = 0; k4 < 32; ++k4) {
    float4 w = *(const float4*)(wrow + 4*k4);
    #pragma unroll
    for (int j = 0; j < 32; ++j) {
      float4 h = *(const float4*)&Hl[t0 + j][4*k4];
      acc[j] += dot4(w, h);
    }
  }
  unsigned short* o = HWp + (((size_t)b*32 + (m >> 2))*64 + t0)*4 + (m & 3);
  #pragma unroll
  for (int j = 0; j < 32; ++j)
    o[j*4] = __bfloat16_as_ushort(__float2bfloat16(acc[j]));
}

// ---------------------------------------------------------------------------
// K2: recurrence. 256 blocks x 8 waves; block owns 8 rows; wave w = row w.
// Weights persist in VGPR fragments (128 VGPR/wave). 3 barriers/step.
// ---------------------------------------------------------------------------
template<bool HB>
__global__ __launch_bounds__(512, 2) void k_main(
    const float* __restrict__ H, const float* __restrict__ Y,
    const unsigned short* __restrict__ HWp, const unsigned short* __restrict__ Hbf,
    const unsigned short* __restrict__ B1f, const unsigned short* __restrict__ B2f,
    const unsigned short* __restrict__ B3f, const float* __restrict__ bio,
    const float* __restrict__ FC2_w, const float* __restrict__ FCin_w,
    const float* __restrict__ FCin_b, const float* __restrict__ W_ih,
    const float* __restrict__ FCout1_b, const float* __restrict__ FCout2_w,
    const float* __restrict__ FCout2_b, float* __restrict__ out, int L)
{
  __shared__ __align__(16) char  AFds[8192];      // A-frags [d|s] bf16 (K=256)
  __shared__ __align__(16) char  AFdc[8192];      // A-frags [d|C] bf16 (K=256)
  __shared__ __align__(16) float a_l[8][128];
  __shared__ __align__(16) float ho_l[8][128];
  __shared__ __align__(16) float gate_l[8][512];
  __shared__ __align__(16) float alpha_l[8][64];
  __shared__ __align__(16) float fc2s[128], fo2s[128], fo1bs[128], fcinC[128];
  __shared__ __align__(16) float bios[512], wihs[512];
  __shared__ float scal[4];

  const int tid = threadIdx.x, w = tid >> 6, lane = tid & 63;

  if (tid < 128) {
    fc2s[tid] = FC2_w[tid]; fo2s[tid] = FCout2_w[tid];
    fo1bs[tid] = FCout1_b[tid]; fcinC[tid] = FCin_w[1 + tid];
  }
  bios[tid] = bio[tid];
  wihs[tid] = W_ih[tid];
  if (tid == 0) { scal[0] = FCin_b[0]; scal[1] = FCout2_b[0]; scal[2] = FCin_w[0]; }
  #pragma unroll
  for (int i = 0; i < 4; ++i) {
    ((int*)AFds)[tid*4 + i] = 0;
    ((int*)AFdc)[tid*4 + i] = 0;
  }
  __syncthreads();

  // persistent weight fragments (held across all 64 steps)
  const bf16x8* B1v = (const bf16x8*)B1f;
  const bf16x8* B2v = (const bf16x8*)B2f;
  const bf16x8* B3v = (const bf16x8*)B3f;
  bf16x8 wA[8], wG[4][4], wO[8];
  #pragma unroll
  for (int kt = 0; kt < 8; ++kt) wA[kt] = B1v[(w*8 + kt)*64 + lane];
  #pragma unroll
  for (int t2 = 0; t2 < 4; ++t2)
    #pragma unroll
    for (int kt = 0; kt < 4; ++kt) wG[t2][kt] = B2v[((w*4 + t2)*4 + kt)*64 + lane];
  #pragma unroll
  for (int kt = 0; kt < 8; ++kt) wO[kt] = B3v[(w*8 + kt)*64 + lane];

  const int b = blockIdx.x * 8 + w;
  const uint2* HWu = (const uint2*)HWp + (size_t)b * 2048;
  const unsigned* Hbu = (const unsigned*)Hbf + (size_t)b * 4096;
  const float2* Hf2 = (const float2*)(H + (size_t)b * 8192);

  float2 sst = {0.f, 0.f};                 // cell state for j=2*lane, 2*lane+1
  const int drow = (lane >> 4) * 4;        // D-frag row base (valid rows < 8)
  const bool dvalid = (lane < 32);
  const int ncb = lane & 15;
  const int j = lane << 1;

  for (int step = 0; step < L; ++step) {
    // ---------- Phase A': a-GEMM + gates-GEMM (read AFds = prev d,s) ----------
    bf16x8 af[8];
    #pragma unroll
    for (int kt = 0; kt < 8; ++kt) af[kt] = *(const bf16x8*)&AFds[afrag_off(kt, lane)];
    f32x4 accA = {0.f,0.f,0.f,0.f};
    #pragma unroll
    for (int kt = 0; kt < 8; ++kt)
      accA = __builtin_amdgcn_mfma_f32_16x16x32_bf16(af[kt], wA[kt], accA, 0, 0, 0);
    f32x4 aG[4];
    #pragma unroll
    for (int t2 = 0; t2 < 4; ++t2) {
      f32x4 acc = {0.f,0.f,0.f,0.f};
      #pragma unroll
      for (int kt = 0; kt < 4; ++kt)
        acc = __builtin_amdgcn_mfma_f32_16x16x32_bf16(af[kt], wG[t2][kt], acc, 0, 0, 0);
      aG[t2] = acc;
    }
    if (dvalid) {
      int nc = w*16 + ncb;
      #pragma unroll
      for (int r2 = 0; r2 < 4; ++r2) a_l[drow + r2][nc] = accA[r2];
      #pragma unroll
      for (int t2 = 0; t2 < 4; ++t2) {
        int ng = (w*4 + t2)*16 + ncb;
        #pragma unroll
        for (int r2 = 0; r2 < 4; ++r2) gate_l[drow + r2][ng] = aG[t2][r2];
      }
    }
    __syncthreads();   // S1

    // ---------- Phase B (wave w = row w): logits, softmax, C, li, LSTM ----------
    float lg = 0.f;
    #pragma unroll 4
    for (int m4 = 0; m4 < 32; ++m4) {
      uint2 u = HWu[m4*64 + lane];
      float4 av = *(const float4*)&a_l[w][m4*4];
      float4 fv = *(const float4*)&fc2s[m4*4];
      lg += fv.x * tanh_fast(av.x + bflo(u.x));
      lg += fv.y * tanh_fast(av.y + bfhi(u.x));
      lg += fv.z * tanh_fast(av.z + bflo(u.y));
      lg += fv.w * tanh_fast(av.w + bfhi(u.y));
    }
    float ex = fexp(lg);                    // |lg| <= ~11: no max-sub needed
    float alpha = ex * frcp(wsum(ex));
    alpha_l[w][lane] = alpha;

    float cx = 0.f, cy = 0.f;
    #pragma unroll 4
    for (int t4 = 0; t4 < 16; ++t4) {
      float4 av = *(const float4*)&alpha_l[w][t4*4];
      if (HB) {
        unsigned h0 = Hbu[(t4*4 + 0)*64 + lane];
        unsigned h1 = Hbu[(t4*4 + 1)*64 + lane];
        unsigned h2 = Hbu[(t4*4 + 2)*64 + lane];
        unsigned h3 = Hbu[(t4*4 + 3)*64 + lane];
        cx += av.x*bflo(h0); cy += av.x*bfhi(h0);
        cx += av.y*bflo(h1); cy += av.y*bfhi(h1);
        cx += av.z*bflo(h2); cy += av.z*bfhi(h2);
        cx += av.w*bflo(h3); cy += av.w*bfhi(h3);
      } else {
        float2 h0 = Hf2[(t4*4 + 0)*64 + lane];
        float2 h1 = Hf2[(t4*4 + 1)*64 + lane];
        float2 h2 = Hf2[(t4*4 + 2)*64 + lane];
        float2 h3 = Hf2[(t4*4 + 3)*64 + lane];
        cx += av.x*h0.x; cy += av.x*h0.y;
        cx += av.y*h1.x; cy += av.y*h1.y;
        cx += av.z*h2.x; cy += av.z*h2.y;
        cx += av.w*h3.x; cy += av.w*h3.y;
      }
    }

    float2 fcv = *(const float2*)&fcinC[j];
    float part = wsum(fcv.x*cx + fcv.y*cy);
    float yt = Y[(size_t)b*64 + step];
    float li = part + scal[2]*yt + scal[0];

    float2 gi = *(const float2*)&gate_l[w][j];
    float2 gf = *(const float2*)&gate_l[w][128 + j];
    float2 gg = *(const float2*)&gate_l[w][256 + j];
    float2 go = *(const float2*)&gate_l[w][384 + j];
    float2 wv, bv;
    wv = *(const float2*)&wihs[j];       bv = *(const float2*)&bios[j];
    gi.x += li*wv.x + bv.x; gi.y += li*wv.y + bv.y;
    wv = *(const float2*)&wihs[128 + j]; bv = *(const float2*)&bios[128 + j];
    gf.x += li*wv.x + bv.x; gf.y += li*wv.y + bv.y;
    wv = *(const float2*)&wihs[256 + j]; bv = *(const float2*)&bios[256 + j];
    gg.x += li*wv.x + bv.x; gg.y += li*wv.y + bv.y;
    wv = *(const float2*)&wihs[384 + j]; bv = *(const float2*)&bios[384 + j];
    go.x += li*wv.x + bv.x; go.y += li*wv.y + bv.y;

    sst.x = sigm_fast(gf.x)*sst.x + sigm_fast(gi.x)*tanh_fast(gg.x);
    sst.y = sigm_fast(gf.y)*sst.y + sigm_fast(gi.y)*tanh_fast(gg.y);
    float dx = sigm_fast(go.x)*tanh_fast(sst.x);
    float dy = sigm_fast(go.y)*tanh_fast(sst.y);

    // publish new d,s,C into fragment tiles (AFds: d@k=j, s@k=128+j; AFdc: d, C)
    unsigned dp = pk2(dx, dy), sp = pk2(sst.x, sst.y), cp = pk2(cx, cy);
    {
      int kt0 = j >> 5, g0 = (j >> 3) & 3, bo = (j & 7) * 2;
      int k1 = 128 + j, kt1 = k1 >> 5, g1 = (k1 >> 3) & 3;
      *(unsigned*)&AFds[afrag_off(kt0, w + 16*g0) + bo] = dp;
      *(unsigned*)&AFdc[afrag_off(kt0, w + 16*g0) + bo] = dp;
      *(unsigned*)&AFds[afrag_off(kt1, w + 16*g1) + bo] = sp;
      *(unsigned*)&AFdc[afrag_off(kt1, w + 16*g1) + bo] = cp;
    }
    __syncthreads();   // S2

    // ---------- Phase C: out-GEMM ----------
    f32x4 accO = {0.f,0.f,0.f,0.f};
    #pragma unroll
    for (int kt = 0; kt < 8; ++kt) {
      bf16x8 afc = *(const bf16x8*)&AFdc[afrag_off(kt, lane)];
      accO = __builtin_amdgcn_mfma_f32_16x16x32_bf16(afc, wO[kt], accO, 0, 0, 0);
    }
    if (dvalid) {
      int nc = w*16 + ncb;
      #pragma unroll
      for (int r2 = 0; r2 < 4; ++r2) ho_l[drow + r2][nc] = accO[r2];
    }
    __syncthreads();   // S3

    // ---------- Phase D: elu + FCout2 reduction ----------
    float2 hv = *(const float2*)&ho_l[w][j];
    float2 bb = *(const float2*)&fo1bs[j];
    float e0 = elu_fast(hv.x + bb.x), e1 = elu_fast(hv.y + bb.y);
    float2 fv2 = *(const float2*)&fo2s[j];
    float op = wsum(fv2.x*e0 + fv2.y*e1);
    if (lane == 0) out[(size_t)b*L + step] = op + scal[1];
  }
}

extern "C" void kernel_launch(void* const* d_in, const int* in_sizes, int n_in,
                              void* d_out, int out_size, void* d_ws, size_t ws_size,
                              hipStream_t stream) {
  const float* H        = (const float*)d_in[0];
  const float* y        = (const float*)d_in[1];
  const float* FC1_w    = (const float*)d_in[2];
  const float* FC1_b    = (const float*)d_in[3];
  const float* FC2_w    = (const float*)d_in[4];
  // d_in[5] = FC2_b (softmax-invariant, unused)
  const float* FCin_w   = (const float*)d_in[6];
  const float* FCin_b   = (const float*)d_in[7];
  const float* W_ih     = (const float*)d_in[8];
  const float* W_hh     = (const float*)d_in[9];
  const float* b_ih     = (const float*)d_in[10];
  const float* b_hh     = (const float*)d_in[11];
  const float* FCout1_w = (const float*)d_in[12];
  const float* FCout1_b = (const float*)d_in[13];
  const float* FCout2_w = (const float*)d_in[14];
  const float* FCout2_b = (const float*)d_in[15];
  float* out = (float*)d_out;
  const int L = out_size / 2048;   // target_length (= 64)

  char* ws = (char*)d_ws;
  // layout: B1f(64K) B2f(128K) B3f(64K) bio(2K) | HWp(32M) | Hbf(32M, optional)
  unsigned short* B1f = (unsigned short*)(ws + 0);
  unsigned short* B2f = (unsigned short*)(ws + 65536);
  unsigned short* B3f = (unsigned short*)(ws + 196608);
  float*          bio = (float*)(ws + 262144);
  unsigned short* HWp = (unsigned short*)(ws + 264192);
  unsigned short* Hbf = (unsigned short*)(ws + 264192 + 33554432);
  const bool hb = ws_size >= (size_t)(264192 + 2*33554432);

  k_prep<<<514, 256, 0, stream>>>(FC1_w, W_hh, FCout1_w, b_ih, b_hh,
                                  B1f, B2f, B3f, bio);
  k_hw<<<2048, 256, 0, stream>>>(H, FC1_w, FC1_b, HWp, hb ? Hbf : nullptr);
  if (hb)
    k_main<true><<<256, 512, 0, stream>>>(H, y, HWp, Hbf, B1f, B2f, B3f, bio,
                                          FC2_w, FCin_w, FCin_b, W_ih,
                                          FCout1_b, FCout2_w, FCout2_b, out, L);
  else
    k_main<false><<<256, 512, 0, stream>>>(H, y, HWp, Hbf, B1f, B2f, B3f, bio,
                                           FC2_w, FCin_w, FCin_b, W_ih,
                                           FCout1_b, FCout2_w, FCout2_b, out, L);
}